// Round 3
// baseline (606.492 us; speedup 1.0000x reference)
//
#include <hip/hip_runtime.h>
#include <hip/hip_bf16.h>

// Problem constants
#define NB   8      // batch
#define NM   288    // Bkk = 32*3*3
#define NN   1152   // Cww = 32*6*6
#define NUV  36     // w*w
#define ND   16

// ws layout (float offsets)
#define OFF_P    0
#define SZ_P     (NB*NUV*NM*ND)      // patches, [b][uv][m][k*4+j]
#define OFF_WT   (OFF_P + SZ_P)
#define SZ_WT    (32*NM*ND)          // W transposed, [z][m][i*4+j]
#define OFF_ACT  (OFF_WT + SZ_WT)
#define SZ_ACT   (NB*NUV*NM)         // act36, [b][uv][m]
#define OFF_L    (OFF_ACT + SZ_ACT)
#define SZ_L     (NB*NN*NM)          // ell = log(act)+LSE_d(log_p), [b][n][m]
#define OFF_LSE  (OFF_L + SZ_L)
#define SZ_LSE   (NB*NM)             // LSE over n, [b][m]
#define OFF_FLAG (OFF_LSE + SZ_LSE)  // dtype flag (int): 1 = inputs are fp32
// total ~4.2M floats = 16.9 MB

#define HALF_LOG_2PI 0.9189385332046727f
#define LOG_NN       7.049254841255839f   // log(1152)
#define NEG_BIG      (-1.0e30f)

// load input element i, interpreting buffer per flag
__device__ __forceinline__ float ldin(const void* p, int i, int f32) {
    return f32 ? ((const float*)p)[i]
               : __bfloat162float(((const __hip_bfloat16*)p)[i]);
}

// Decide whether inputs are fp32 or bf16 by inspecting poses (~N(0,1)).
// True bf16 N(0,1): bf16 exponent field < 133 (|x| < 64) for all samples.
// fp32 data misread as bf16: even-index elements are fp32 low-mantissa halves
// -> uniform random exponent -> ~half have |x|>=64 or NaN.
__global__ void detect_kernel(const unsigned short* __restrict__ poses_u16,
                              int* __restrict__ flag) {
    if (blockIdx.x == 0 && threadIdx.x == 0) {
        int wild = 0;
        for (int i = 0; i < 64; ++i) {
            int ex = (poses_u16[i] >> 7) & 0xFF;
            if (ex >= 133) ++wild;
        }
        *flag = (wild >= 4) ? 1 : 0;
    }
}

__global__ void prep_kernel(const void* __restrict__ poses,
                            const void* __restrict__ acts,
                            const void* __restrict__ Wb,
                            float* __restrict__ P, float* __restrict__ Wt,
                            float* __restrict__ A36,
                            const int* __restrict__ flagp)
{
    const int f32 = *flagp;
    int t = blockIdx.x * 256 + threadIdx.x;
    if (t < SZ_P) {
        // P[b][uv][m][k*4+j] = patch[b,s,x,y,u,v,j,k]
        int kj = t & 15;
        int m  = (t >> 4) % NM;
        int uv = ((t >> 4) / NM) % NUV;
        int b  = t / (16 * NM * NUV);
        int k = kj >> 2, j = kj & 3;
        int u = uv / 6, vv = uv % 6;
        int s = m / 9, x = (m % 9) / 3, y = m % 3;
        // scrambled torch view: (16,w,w) block re-read as (w,w,4,4)
        int idx = u * 96 + vv * 16 + j * 4 + k;
        int c = idx / 36, rem = idx % 36;
        int wi = rem / 6, wj = rem % 6;
        int src = (((b * 16 + c) * 32 + s) * 14 + (2 * wi + x)) * 14 + (2 * wj + y);
        P[t] = ldin(poses, src, f32);
    } else if (t < SZ_P + SZ_WT) {
        int q = t - SZ_P;
        int ij = q & 15;
        int m  = (q >> 4) % NM;
        int z  = (q >> 4) / NM;
        Wt[q] = ldin(Wb, m * 512 + z * 16 + ij, f32);
    } else if (t < SZ_P + SZ_WT + SZ_ACT) {
        int q = t - SZ_P - SZ_WT;
        int m  = q % NM;
        int uv = (q / NM) % NUV;
        int b  = q / (NM * NUV);
        int u = uv / 6, vv = uv % 6;
        int s = m / 9, x = (m % 9) / 3, y = m % 3;
        A36[q] = ldin(acts, ((b * 32 + s) * 14 + (2 * u + x)) * 14 + (2 * vv + y), f32);
    }
}

// One block per (b,n). 256 threads: d = tid&15, g = tid>>4; each thread owns
// 18 votes (m = g+16*mm) in registers.
__global__ __launch_bounds__(256, 3) void em_iter(
    const float* __restrict__ wsP, const float* __restrict__ wsWt,
    const float* __restrict__ wsA, float* __restrict__ wsL,
    const float* __restrict__ wsLSE,
    const void* __restrict__ beta_v,
    const void* __restrict__ beta_a,
    const void* __restrict__ lambda_,
    void* __restrict__ outv, const int* __restrict__ flagp, int iter)
{
    __shared__ float Wl[NM * ND];   // 18432 B
    __shared__ float Pl[NM * ND];   // 18432 B
    __shared__ float la[NM];        // log(act)
    __shared__ float tl[NM];        // t_m = log(R*act)
    __shared__ float wl[NM];        // w~ = exp(t - maxt)
    __shared__ float red[16][17];
    __shared__ float redw[4];
    __shared__ float mul[16];
    __shared__ float ssl[16];
    __shared__ float nhil[16];
    __shared__ float ltl[16];

    const int tid = threadIdx.x;
    const int bn  = blockIdx.x;
    const int b   = bn / NN;
    const int n   = bn % NN;
    const int z   = n / NUV;
    const int uv  = n % NUV;

    // stage W[z] and P[b][uv] slices (coalesced float4)
    {
        const float4* Wsrc = (const float4*)(wsWt + z * (NM * ND));
        const float4* Psrc = (const float4*)(wsP + (b * NUV + uv) * (NM * ND));
        float4* Wl4 = (float4*)Wl;
        float4* Pl4 = (float4*)Pl;
        for (int t = tid; t < NM * ND / 4; t += 256) { Wl4[t] = Wsrc[t]; Pl4[t] = Psrc[t]; }
    }
    // t_m = ell - LSE_m + log(act)   (iter 0: log(act) - log(NN))
    {
        const float* actrow = wsA + (b * NUV + uv) * NM;
        const float* lrow   = wsL + (size_t)(b * NN + n) * NM;
        const float* lserow = wsLSE + b * NM;
        for (int m = tid; m < NM; m += 256) {
            float lact = __logf(actrow[m]);
            la[m] = lact;
            tl[m] = (iter == 0) ? (lact - LOG_NN) : (lrow[m] - lserow[m] + lact);
        }
    }
    __syncthreads();

    // block max of t
    float mx = NEG_BIG;
    for (int m = tid; m < NM; m += 256) mx = fmaxf(mx, tl[m]);
#pragma unroll
    for (int off = 32; off > 0; off >>= 1) mx = fmaxf(mx, __shfl_xor(mx, off));
    if ((tid & 63) == 0) redw[tid >> 6] = mx;
    __syncthreads();
    const float maxt = fmaxf(fmaxf(redw[0], redw[1]), fmaxf(redw[2], redw[3]));
    __syncthreads();

    // w~ = exp(t - maxt): max element is exactly 1 -> sums >= 1, no 0/0
    for (int m = tid; m < NM; m += 256) wl[m] = __expf(tl[m] - maxt);
    __syncthreads();

    const int d  = tid & 15, g = tid >> 4;
    const int i4 = d & 12;            // (d>>2)*4
    const int k4 = (d & 3) << 2;

    // votes in registers: v[mm] for m = g+16*mm; vote[i][k] = sum_j W[i][j]P[j][k]
    float v[18];
#pragma unroll
    for (int mm = 0; mm < 18; ++mm) {
        int m = g + (mm << 4);
        const float* wr = &Wl[(m << 4) + i4];
        const float* pr = &Pl[(m << 4) + k4];
        v[mm] = wr[0] * pr[0] + wr[1] * pr[1] + wr[2] * pr[2] + wr[3] * pr[3];
    }

    // sumW
    float sl = 0.f;
    for (int m = tid; m < NM; m += 256) sl += wl[m];
#pragma unroll
    for (int off = 32; off > 0; off >>= 1) sl += __shfl_xor(sl, off);
    if ((tid & 63) == 0) redw[tid >> 6] = sl;
    __syncthreads();
    const float sumW = (redw[0] + redw[1]) + (redw[2] + redw[3]);

    // mu[d] = sum_m w~ v / sumW
    float acc = 0.f;
#pragma unroll
    for (int mm = 0; mm < 18; ++mm) acc += wl[g + (mm << 4)] * v[mm];
    red[g][d] = acc;
    __syncthreads();
    if (tid < 16) {
        float s = 0.f;
#pragma unroll
        for (int gg = 0; gg < 16; ++gg) s += red[gg][tid];
        mul[tid] = s / sumW;
    }
    __syncthreads();
    const float mud = mul[d];

    // sigma_sq[d]
    acc = 0.f;
#pragma unroll
    for (int mm = 0; mm < 18; ++mm) {
        float df = v[mm] - mud;
        acc += wl[g + (mm << 4)] * df * df;
    }
    red[g][d] = acc;
    __syncthreads();
    if (tid < 16) {
        float ss = 0.f;
#pragma unroll
        for (int gg = 0; gg < 16; ++gg) ss += red[gg][tid];
        ss = fmaxf(ss / sumW, 1e-30f);   // clamp: no-op when benign
        ssl[tid]  = ss;
        nhil[tid] = -0.5f / ss;
        ltl[tid]  = -0.5f * __logf(ss) - HALF_LOG_2PI;
    }
    __syncthreads();

    if (iter < 3) {
        // ell[m] = log(act) + LSE_d(log_p)
        const float nhi = nhil[d], lt = ltl[d];
        float* lw = wsL + (size_t)(b * NN + n) * NM;
#pragma unroll
        for (int mm = 0; mm < 18; ++mm) {
            float df = v[mm] - mud;
            float lp = fmaxf(df * df * nhi + lt, NEG_BIG);  // finite
            float M = lp;
            M = fmaxf(M, __shfl_xor(M, 1));
            M = fmaxf(M, __shfl_xor(M, 2));
            M = fmaxf(M, __shfl_xor(M, 4));
            M = fmaxf(M, __shfl_xor(M, 8));
            float e = __expf(lp - M);
            e += __shfl_xor(e, 1);
            e += __shfl_xor(e, 2);
            e += __shfl_xor(e, 4);
            e += __shfl_xor(e, 8);
            if (d == 0) {
                int m = g + (mm << 4);
                lw[m] = la[m] + M + __logf(e);
            }
        }
    } else {
        const int f32 = *flagp;
        if (tid < 16) {
            if (f32) ((float*)outv)[(bn << 4) + tid] = mul[tid];
            else ((__hip_bfloat16*)outv)[(bn << 4) + tid] = __float2bfloat16(mul[tid]);
        }
        if (tid == 0) {
            float sumR = __expf(maxt) * sumW;   // true sum_R (maxt <= 0)
            float bv = ldin(beta_v, n, f32);
            float c = 0.f;
#pragma unroll
            for (int dd = 0; dd < 16; ++dd) c += bv + __logf(ssl[dd]);
            c *= sumR;
            float lam = ldin(lambda_, 0, f32);
            float ba  = ldin(beta_a, n, f32);
            float ao  = 1.f / (1.f + __expf(-(lam * (ba - c))));
            int oi = NB * NN * ND + b * NN + n;
            if (f32) ((float*)outv)[oi] = ao;
            else ((__hip_bfloat16*)outv)[oi] = __float2bfloat16(ao);
        }
    }
}

// LSE over n of ell[b][n][m], one block per (b,m)
__global__ __launch_bounds__(256) void lse_kernel(const float* __restrict__ L,
                                                  float* __restrict__ LSE)
{
    __shared__ float col[NN];
    __shared__ float redw[4];
    const int tid = threadIdx.x;
    const int b = blockIdx.x / NM;
    const int m = blockIdx.x % NM;
    const float* base = L + (size_t)b * NN * NM + m;
    for (int n = tid; n < NN; n += 256) col[n] = base[(size_t)n * NM];
    __syncthreads();

    float mx = NEG_BIG;
    for (int n = tid; n < NN; n += 256) mx = fmaxf(mx, col[n]);
#pragma unroll
    for (int off = 32; off > 0; off >>= 1) mx = fmaxf(mx, __shfl_xor(mx, off));
    if ((tid & 63) == 0) redw[tid >> 6] = mx;
    __syncthreads();
    const float M = fmaxf(fmaxf(redw[0], redw[1]), fmaxf(redw[2], redw[3]));
    __syncthreads();

    float s = 0.f;
    for (int n = tid; n < NN; n += 256) s += __expf(col[n] - M);
#pragma unroll
    for (int off = 32; off > 0; off >>= 1) s += __shfl_xor(s, off);
    if ((tid & 63) == 0) redw[tid >> 6] = s;
    __syncthreads();
    if (tid == 0) {
        float S = (redw[0] + redw[1]) + (redw[2] + redw[3]);
        LSE[blockIdx.x] = M + __logf(S);
    }
}

extern "C" void kernel_launch(void* const* d_in, const int* in_sizes, int n_in,
                              void* d_out, int out_size, void* d_ws, size_t ws_size,
                              hipStream_t stream)
{
    const void* poses = d_in[0];
    const void* acts  = d_in[1];
    const void* lam   = d_in[2];
    const void* Wb    = d_in[3];
    const void* bv    = d_in[4];
    const void* ba    = d_in[5];

    float* ws  = (float*)d_ws;
    float* P   = ws + OFF_P;
    float* Wt  = ws + OFF_WT;
    float* A36 = ws + OFF_ACT;
    float* L   = ws + OFF_L;
    float* LSE = ws + OFF_LSE;
    int*  flag = (int*)(ws + OFF_FLAG);

    detect_kernel<<<1, 64, 0, stream>>>((const unsigned short*)poses, flag);

    // (SZ_P+SZ_WT+SZ_ACT) = 1,557,504 = 6084*256 exactly
    prep_kernel<<<6084, 256, 0, stream>>>(poses, acts, Wb, P, Wt, A36, flag);

    for (int it = 0; it < 4; ++it) {
        em_iter<<<NB * NN, 256, 0, stream>>>(P, Wt, A36, L, LSE, bv, ba, lam,
                                             d_out, flag, it);
        if (it < 3) {
            lse_kernel<<<NB * NM, 256, 0, stream>>>(L, LSE);
        }
    }
}

// Round 4
// 271.309 us; speedup vs baseline: 2.2354x; 2.2354x over previous
//
#include <hip/hip_runtime.h>
#include <hip/hip_bf16.h>

// Problem constants
#define NB   8      // batch
#define NM   288    // Bkk = 32*3*3
#define NN   1152   // Cww = 32*6*6
#define NUV  36     // w*w
#define ND   16

// ws layout (float offsets)
#define OFF_P    0
#define SZ_P     (NB*NUV*NM*ND)      // patches, [b][uv][m][k*4+j]
#define OFF_WT   (OFF_P + SZ_P)
#define SZ_WT    (32*NM*ND)          // W transposed, [z][m][i*4+j]
#define OFF_ACT  (OFF_WT + SZ_WT)
#define SZ_ACT   (NB*NUV*NM)         // act36, [b][uv][m]
#define OFF_L    (OFF_ACT + SZ_ACT)
#define SZ_L     (NB*NN*NM)          // ell = log(act)+LSE_d(log_p), [b][n][m]
#define OFF_LSE  (OFF_L + SZ_L)
#define SZ_LSE   (NB*NM)             // LSE over n, [b][m]
#define OFF_FLAG (OFF_LSE + SZ_LSE)  // dtype flag (int): 1 = inputs are fp32

#define HALF_LOG_2PI 0.9189385332046727f
#define LOG_NN       7.049254841255839f   // log(1152)
#define NEG_BIG      (-1.0e30f)

// load input element i, interpreting buffer per flag
__device__ __forceinline__ float ldin(const void* p, int i, int f32) {
    return f32 ? ((const float*)p)[i]
               : __bfloat162float(((const __hip_bfloat16*)p)[i]);
}

// dtype sniff (r3-verified; flag==0 on this harness, kept as-is)
__global__ void detect_kernel(const unsigned short* __restrict__ poses_u16,
                              int* __restrict__ flag) {
    if (blockIdx.x == 0 && threadIdx.x == 0) {
        int wild = 0;
        for (int i = 0; i < 64; ++i) {
            int ex = (poses_u16[i] >> 7) & 0xFF;
            if (ex >= 133) ++wild;
        }
        *flag = (wild >= 4) ? 1 : 0;
    }
}

__global__ void prep_kernel(const void* __restrict__ poses,
                            const void* __restrict__ acts,
                            const void* __restrict__ Wb,
                            float* __restrict__ P, float* __restrict__ Wt,
                            float* __restrict__ A36,
                            const int* __restrict__ flagp)
{
    const int f32 = *flagp;
    int t = blockIdx.x * 256 + threadIdx.x;
    if (t < SZ_P) {
        // P[b][uv][m][k*4+j] = patch[b,s,x,y,u,v,j,k]
        int kj = t & 15;
        int m  = (t >> 4) % NM;
        int uv = ((t >> 4) / NM) % NUV;
        int b  = t / (16 * NM * NUV);
        int k = kj >> 2, j = kj & 3;
        int u = uv / 6, vv = uv % 6;
        int s = m / 9, x = (m % 9) / 3, y = m % 3;
        // scrambled torch view: (16,w,w) block re-read as (w,w,4,4)
        int idx = u * 96 + vv * 16 + j * 4 + k;
        int c = idx / 36, rem = idx % 36;
        int wi = rem / 6, wj = rem % 6;
        int src = (((b * 16 + c) * 32 + s) * 14 + (2 * wi + x)) * 14 + (2 * wj + y);
        P[t] = ldin(poses, src, f32);
    } else if (t < SZ_P + SZ_WT) {
        int q = t - SZ_P;
        int ij = q & 15;
        int m  = (q >> 4) % NM;
        int z  = (q >> 4) / NM;
        Wt[q] = ldin(Wb, m * 512 + z * 16 + ij, f32);
    } else if (t < SZ_P + SZ_WT + SZ_ACT) {
        int q = t - SZ_P - SZ_WT;
        int m  = q % NM;
        int uv = (q / NM) % NUV;
        int b  = q / (NM * NUV);
        int u = uv / 6, vv = uv % 6;
        int s = m / 9, x = (m % 9) / 3, y = m % 3;
        A36[q] = ldin(acts, ((b * 32 + s) * 14 + (2 * u + x)) * 14 + (2 * vv + y), f32);
    }
}

#define RS 292   // LDS column stride (banks: writes conflict-free; reads <=4-way)

// One block per (b,n). 288 threads; thread tid owns capsule m = tid:
// W/P rows global->registers, 16 votes in registers, LSE over d serial in
// registers (no shuffles). Cross-thread: one LDS transpose for mu / E[v^2].
__global__ __launch_bounds__(288, 4) void em_iter(
    const float* __restrict__ wsP, const float* __restrict__ wsWt,
    const float* __restrict__ wsA, float* __restrict__ wsL,
    const float* __restrict__ wsLSE,
    const void* __restrict__ beta_v,
    const void* __restrict__ beta_a,
    const void* __restrict__ lambda_,
    void* __restrict__ outv, const int* __restrict__ flagp, int iter)
{
    __shared__ float red[RS * 17];   // col-major: red[col*RS + m]; cols 0..15 = v[d], col 16 = w
    __shared__ float tmax[16];
    __shared__ float paru[NM];       // partial sum(w*v) per (d,chunk)
    __shared__ float parv[NM];       // partial sum(w*v*v)
    __shared__ float paruW[18];      // partial sum(w) per chunk
    __shared__ float mul[16], nhil[16], ltl[16], ssl[16];
    __shared__ float sumWl;

    const int tid = threadIdx.x;          // == m
    const int bn  = blockIdx.x;
    const int b   = bn / NN;
    const int n   = bn % NN;
    const int z   = n / NUV;
    const int uv  = n % NUV;

    // per-m global loads, issued early (64B/lane, dense across the wave)
    float4 w0, w1, w2, w3, p0, p1, p2, p3;
    {
        const float4* W4 = (const float4*)(wsWt + ((z * NM + tid) << 4));
        const float4* P4 = (const float4*)(wsP + (((b * NUV + uv) * NM + tid) << 4));
        w0 = W4[0]; w1 = W4[1]; w2 = W4[2]; w3 = W4[3];
        p0 = P4[0]; p1 = P4[1]; p2 = P4[2]; p3 = P4[3];
    }
    const float lact = __logf(wsA[(b * NUV + uv) * NM + tid]);
    float t;
    if (iter == 0) t = lact - LOG_NN;
    else t = wsL[(size_t)(b * NN + n) * NM + tid] - wsLSE[b * NM + tid] + lact;

    // block max of t (LDS 2-stage; red[0..287] free until vote writes)
    red[tid] = t;
    __syncthreads();                                        // B1
    if (tid < 16) {
        float mx = red[tid * 18];
        for (int c = 1; c < 18; ++c) mx = fmaxf(mx, red[tid * 18 + c]);
        tmax[tid] = mx;
    }
    __syncthreads();                                        // B2
    float maxt = tmax[0];
#pragma unroll
    for (int dd = 1; dd < 16; ++dd) maxt = fmaxf(maxt, tmax[dd]);
    const float w = __expf(t - maxt);   // max element = 1 -> sums >= 1, no 0/0

    // votes v[i*4+k] = sum_j W[i][j] P[j][k]  (all in registers)
#define DOT4(a, c) ((a).x * (c).x + (a).y * (c).y + (a).z * (c).z + (a).w * (c).w)
    float v[16];
    v[ 0] = DOT4(w0, p0); v[ 1] = DOT4(w0, p1); v[ 2] = DOT4(w0, p2); v[ 3] = DOT4(w0, p3);
    v[ 4] = DOT4(w1, p0); v[ 5] = DOT4(w1, p1); v[ 6] = DOT4(w1, p2); v[ 7] = DOT4(w1, p3);
    v[ 8] = DOT4(w2, p0); v[ 9] = DOT4(w2, p1); v[10] = DOT4(w2, p2); v[11] = DOT4(w2, p3);
    v[12] = DOT4(w3, p0); v[13] = DOT4(w3, p1); v[14] = DOT4(w3, p2); v[15] = DOT4(w3, p3);

    // transpose to LDS (column-major, conflict-free b32 writes)
#pragma unroll
    for (int dd = 0; dd < 16; ++dd) red[dd * RS + tid] = v[dd];
    red[16 * RS + tid] = w;
    __syncthreads();                                        // B3

    // column sums: thread = d*18 + c sums rows 16c..16c+15 of column d
    {
        const int d = tid / 18, c = tid % 18;
        const float* vcol = &red[d * RS + (c << 4)];
        const float* wcol = &red[16 * RS + (c << 4)];
        float s1 = 0.f, s2 = 0.f, sw = 0.f;
#pragma unroll
        for (int q = 0; q < 16; ++q) {
            float ww = wcol[q];
            float vv = vcol[q];
            float t1 = ww * vv;
            s1 += t1; s2 += t1 * vv; sw += ww;
        }
        paru[tid] = s1;
        parv[tid] = s2;
        if (d == 0) paruW[c] = sw;
    }
    __syncthreads();                                        // B4
    if (tid < 16) {
        float sW = 0.f, S1 = 0.f, S2 = 0.f;
#pragma unroll
        for (int c = 0; c < 18; ++c) {
            sW += paruW[c];
            S1 += paru[tid * 18 + c];
            S2 += parv[tid * 18 + c];
        }
        float mu = S1 / sW;
        float q2 = S2 / sW;
        float ss = fmaxf(q2 - mu * mu, 1e-30f);   // E[v^2]-mu^2; clamp no-op when benign
        mul[tid]  = mu;
        ssl[tid]  = ss;
        nhil[tid] = -0.5f / ss;
        ltl[tid]  = -0.5f * __logf(ss) - HALF_LOG_2PI;
        if (tid == 0) sumWl = sW;
    }
    __syncthreads();                                        // B5

    if (iter < 3) {
        // ell[m] = log(act) + LSE_d(log_p) -- serial over d, zero shuffles
        float lp[16];
        float M = NEG_BIG;
#pragma unroll
        for (int dd = 0; dd < 16; ++dd) {
            float df = v[dd] - mul[dd];
            lp[dd] = df * df * nhil[dd] + ltl[dd];
            M = fmaxf(M, lp[dd]);
        }
        float s = 0.f;
#pragma unroll
        for (int dd = 0; dd < 16; ++dd) s += __expf(lp[dd] - M);
        wsL[(size_t)(b * NN + n) * NM + tid] = lact + M + __logf(s);
    } else {
        const int f32 = *flagp;
        if (tid < 16) {
            if (f32) ((float*)outv)[(bn << 4) + tid] = mul[tid];
            else ((__hip_bfloat16*)outv)[(bn << 4) + tid] = __float2bfloat16(mul[tid]);
        }
        if (tid == 0) {
            float sumR = __expf(maxt) * sumWl;   // true sum_R (maxt <= 0)
            float bv = ldin(beta_v, n, f32);
            float c = 0.f;
#pragma unroll
            for (int dd = 0; dd < 16; ++dd) c += bv + __logf(ssl[dd]);
            c *= sumR;
            float lam = ldin(lambda_, 0, f32);
            float ba  = ldin(beta_a, n, f32);
            float ao  = 1.f / (1.f + __expf(-(lam * (ba - c))));
            int oi = NB * NN * ND + b * NN + n;
            if (f32) ((float*)outv)[oi] = ao;
            else ((__hip_bfloat16*)outv)[oi] = __float2bfloat16(ao);
        }
    }
}

// LSE over n of ell[b][n][m], one block per (b,m)
__global__ __launch_bounds__(256) void lse_kernel(const float* __restrict__ L,
                                                  float* __restrict__ LSE)
{
    __shared__ float col[NN];
    __shared__ float redw[4];
    const int tid = threadIdx.x;
    const int b = blockIdx.x / NM;
    const int m = blockIdx.x % NM;
    const float* base = L + (size_t)b * NN * NM + m;
    for (int n = tid; n < NN; n += 256) col[n] = base[(size_t)n * NM];
    __syncthreads();

    float mx = NEG_BIG;
    for (int n = tid; n < NN; n += 256) mx = fmaxf(mx, col[n]);
#pragma unroll
    for (int off = 32; off > 0; off >>= 1) mx = fmaxf(mx, __shfl_xor(mx, off));
    if ((tid & 63) == 0) redw[tid >> 6] = mx;
    __syncthreads();
    const float M = fmaxf(fmaxf(redw[0], redw[1]), fmaxf(redw[2], redw[3]));
    __syncthreads();

    float s = 0.f;
    for (int n = tid; n < NN; n += 256) s += __expf(col[n] - M);
#pragma unroll
    for (int off = 32; off > 0; off >>= 1) s += __shfl_xor(s, off);
    if ((tid & 63) == 0) redw[tid >> 6] = s;
    __syncthreads();
    if (tid == 0) {
        float S = (redw[0] + redw[1]) + (redw[2] + redw[3]);
        LSE[blockIdx.x] = M + __logf(S);
    }
}

extern "C" void kernel_launch(void* const* d_in, const int* in_sizes, int n_in,
                              void* d_out, int out_size, void* d_ws, size_t ws_size,
                              hipStream_t stream)
{
    const void* poses = d_in[0];
    const void* acts  = d_in[1];
    const void* lam   = d_in[2];
    const void* Wb    = d_in[3];
    const void* bv    = d_in[4];
    const void* ba    = d_in[5];

    float* ws  = (float*)d_ws;
    float* P   = ws + OFF_P;
    float* Wt  = ws + OFF_WT;
    float* A36 = ws + OFF_ACT;
    float* L   = ws + OFF_L;
    float* LSE = ws + OFF_LSE;
    int*  flag = (int*)(ws + OFF_FLAG);

    detect_kernel<<<1, 64, 0, stream>>>((const unsigned short*)poses, flag);

    // (SZ_P+SZ_WT+SZ_ACT) = 1,557,504 = 6084*256 exactly
    prep_kernel<<<6084, 256, 0, stream>>>(poses, acts, Wb, P, Wt, A36, flag);

    for (int it = 0; it < 4; ++it) {
        em_iter<<<NB * NN, 288, 0, stream>>>(P, Wt, A36, L, LSE, bv, ba, lam,
                                             d_out, flag, it);
        if (it < 3) {
            lse_kernel<<<NB * NM, 256, 0, stream>>>(L, LSE);
        }
    }
}

// Round 5
// 270.170 us; speedup vs baseline: 2.2449x; 1.0042x over previous
//
#include <hip/hip_runtime.h>
#include <hip/hip_bf16.h>

// Problem constants
#define NB   8      // batch
#define NM   288    // Bkk = 32*3*3
#define NN   1152   // Cww = 32*6*6
#define NUV  36     // w*w
#define ND   16

// ws layout (float offsets)
#define OFF_P    0
#define SZ_P     (NB*NUV*NM*ND)      // patches, [b][uv][m][k*4+j]
#define OFF_WT   (OFF_P + SZ_P)
#define SZ_WT    (32*NM*ND)          // W transposed, [z][m][i*4+j]
#define OFF_ACT  (OFF_WT + SZ_WT)
#define SZ_ACT   (NB*NUV*NM)         // act36, [b][uv][m]
#define OFF_L    (OFF_ACT + SZ_ACT)
#define SZ_L     (NB*NN*NM)          // ell = log(act)+LSE_d(log_p), [b][n][m]
#define OFF_LSE  (OFF_L + SZ_L)
#define SZ_LSE   (NB*NM)             // LSE over n, [b][m]
#define OFF_FLAG (OFF_LSE + SZ_LSE)  // dtype flag (int): 1 = inputs are fp32

#define HALF_LOG_2PI 0.9189385332046727f
#define LOG_NN       7.049254841255839f   // log(1152)
#define NEG_BIG      (-1.0e30f)

// load input element i, interpreting buffer per flag
__device__ __forceinline__ float ldin(const void* p, int i, int f32) {
    return f32 ? ((const float*)p)[i]
               : __bfloat162float(((const __hip_bfloat16*)p)[i]);
}

// dtype sniff (r3/r4-verified: flag==0 on this harness; kept for safety)
__global__ void detect_kernel(const unsigned short* __restrict__ poses_u16,
                              int* __restrict__ flag) {
    if (blockIdx.x == 0 && threadIdx.x == 0) {
        int wild = 0;
        for (int i = 0; i < 64; ++i) {
            int ex = (poses_u16[i] >> 7) & 0xFF;
            if (ex >= 133) ++wild;
        }
        *flag = (wild >= 4) ? 1 : 0;
    }
}

// (b,s)-tiled prep: stage poses[b,:,s,:,:] (12.5 KB) + acts[b,s,:,:] in LDS,
// emit P in coalesced 144-float runs. Blocks 256..291 transpose W.
__global__ __launch_bounds__(256) void prep_kernel(
    const void* __restrict__ poses, const void* __restrict__ acts,
    const void* __restrict__ Wb, float* __restrict__ P,
    float* __restrict__ Wt, float* __restrict__ A36,
    const int* __restrict__ flagp)
{
    const int f32 = *flagp;
    const int blk = blockIdx.x;
    const int tid = threadIdx.x;
    if (blk < 256) {
        __shared__ float ps[16 * 196];
        __shared__ float asld[196];
        const int b = blk >> 5, s = blk & 31;
        for (int e = tid; e < 16 * 196; e += 256) {
            int c = e / 196, hw = e % 196;
            ps[e] = ldin(poses, ((b * 16 + c) * 32 + s) * 196 + hw, f32);
        }
        for (int e = tid; e < 196; e += 256)
            asld[e] = ldin(acts, (b * 32 + s) * 196 + e, f32);
        __syncthreads();
        // P: 36 uv * 9 xy * 16 kj outputs for m = s*9+xy
        for (int o = tid; o < 5184; o += 256) {
            int uv = o / 144, r = o % 144, xy = r >> 4, kj = r & 15;
            int u = uv / 6, vv2 = uv % 6;
            int x = xy / 3, y = xy % 3;
            int k = kj >> 2, j = kj & 3;
            int idx = u * 96 + vv2 * 16 + j * 4 + k;   // torch view scramble
            int c = idx / 36, rem = idx % 36;
            int wi = rem / 6, wj = rem % 6;
            P[((b * 36 + uv) * 288 + s * 9 + xy) * 16 + kj] =
                ps[c * 196 + (2 * wi + x) * 14 + (2 * wj + y)];
        }
        for (int o = tid; o < 324; o += 256) {
            int uv = o / 9, xy = o % 9;
            int u = uv / 6, vv2 = uv % 6;
            int x = xy / 3, y = xy % 3;
            A36[(b * 36 + uv) * 288 + s * 9 + xy] = asld[(2 * u + x) * 14 + (2 * vv2 + y)];
        }
    } else {
        // Wt[z][m][ij]: 36 blocks x 256 threads = 9216 (z,m) pairs, 16 each
        int idx = (blk - 256) * 256 + tid;    // 0..9215
        int z = idx / 288, m = idx % 288;
        float* dst = &Wt[idx * 16];
#pragma unroll
        for (int e = 0; e < 16; ++e)
            dst[e] = ldin(Wb, m * 512 + z * 16 + e, f32);
    }
}

#define DOT4(a, c) ((a).x * (c).x + (a).y * (c).y + (a).z * (c).z + (a).w * (c).w)

// One block per (b,n). 288 threads; thread tid owns capsule m = tid.
// LDS transpose is m-major stride-17: writes 2-way (free), colsum reads
// lane-consecutive (conflict-free), w column is a broadcast.
__global__ __launch_bounds__(288, 7) void em_iter(
    const float* __restrict__ wsP, const float* __restrict__ wsWt,
    const float* __restrict__ wsA, float* __restrict__ wsL,
    const float* __restrict__ wsLSE,
    const void* __restrict__ beta_v,
    const void* __restrict__ beta_a,
    const void* __restrict__ lambda_,
    void* __restrict__ outv, const int* __restrict__ flagp, int iter)
{
    __shared__ float red[NM * 17];   // [m][col]: cols 0..15 = v[d], 16 = w. 19.6 KB
    __shared__ float tmax[16];
    __shared__ float paru[NM];       // [d][c] partial sum(w*v)
    __shared__ float parv[NM];       // [d][c] partial sum(w*v*v)
    __shared__ float paruW[18];      // [c] partial sum(w)
    __shared__ float mul[16], nhil[16], ltl[16], ssl[16];
    __shared__ float sumWl;

    const int tid = threadIdx.x;          // == m
    const int bn  = blockIdx.x;
    const int b   = bn / NN;
    const int n   = bn % NN;
    const int z   = n / NUV;
    const int uv  = n % NUV;

    // per-m global loads issued first (128 B/lane, L2-hot)
    const float4* W4 = (const float4*)(wsWt + ((z * NM + tid) << 4));
    const float4* P4 = (const float4*)(wsP + (((b * NUV + uv) * NM + tid) << 4));
    float4 w0 = W4[0], w1 = W4[1], w2 = W4[2], w3 = W4[3];
    float4 p0 = P4[0], p1 = P4[1], p2 = P4[2], p3 = P4[3];

    const float lact = __logf(wsA[(b * NUV + uv) * NM + tid]);
    float t;
    if (iter == 0) t = lact - LOG_NN;
    else t = wsL[(size_t)(b * NN + n) * NM + tid] - wsLSE[b * NM + tid] + lact;
    red[tid] = t;   // tarr (overwritten by transpose only after B2)

    // votes v[i*4+k] = sum_j W[i][j] P[j][k] — independent of t, fills B1 latency
    float v[16];
    v[ 0] = DOT4(w0, p0); v[ 1] = DOT4(w0, p1); v[ 2] = DOT4(w0, p2); v[ 3] = DOT4(w0, p3);
    v[ 4] = DOT4(w1, p0); v[ 5] = DOT4(w1, p1); v[ 6] = DOT4(w1, p2); v[ 7] = DOT4(w1, p3);
    v[ 8] = DOT4(w2, p0); v[ 9] = DOT4(w2, p1); v[10] = DOT4(w2, p2); v[11] = DOT4(w2, p3);
    v[12] = DOT4(w3, p0); v[13] = DOT4(w3, p1); v[14] = DOT4(w3, p2); v[15] = DOT4(w3, p3);

    __syncthreads();                                        // B1
    if (tid < 16) {
        float mx = red[tid * 18];
#pragma unroll
        for (int cc = 1; cc < 18; ++cc) mx = fmaxf(mx, red[tid * 18 + cc]);
        tmax[tid] = mx;
    }
    __syncthreads();                                        // B2
    float maxt = tmax[0];
#pragma unroll
    for (int dd = 1; dd < 16; ++dd) maxt = fmaxf(maxt, tmax[dd]);
    const float w = __expf(t - maxt);   // max element = 1 -> sumW >= 1, no 0/0

    // transpose: m-major stride 17 (odd -> bank-bijective, free)
#pragma unroll
    for (int dd = 0; dd < 16; ++dd) red[tid * 17 + dd] = v[dd];
    red[tid * 17 + 16] = w;
    __syncthreads();                                        // B3

    // column sums: thread (d = tid&15, c = tid>>4) sums m = 16c..16c+15
    {
        const int d = tid & 15, c = tid >> 4;
        const float* base = &red[(c << 4) * 17];
        float s1 = 0.f, s2 = 0.f, sw = 0.f;
#pragma unroll
        for (int q = 0; q < 16; ++q) {
            float ww = base[q * 17 + 16];   // broadcast across the 16 d-lanes
            float vv = base[q * 17 + d];    // lane-consecutive: conflict-free
            float t1 = ww * vv;
            s1 += t1; s2 += t1 * vv; sw += ww;
        }
        paru[d * 18 + c] = s1;
        parv[d * 18 + c] = s2;
        if (d == 0) paruW[c] = sw;
    }
    __syncthreads();                                        // B4
    if (tid < 16) {
        float sW = 0.f, S1 = 0.f, S2 = 0.f;
#pragma unroll
        for (int c = 0; c < 18; ++c) {
            sW += paruW[c];
            S1 += paru[tid * 18 + c];
            S2 += parv[tid * 18 + c];
        }
        float mu = S1 / sW;
        float q2 = S2 / sW;
        float ss = fmaxf(q2 - mu * mu, 1e-30f);   // E[v^2]-mu^2 (r4-verified)
        mul[tid]  = mu;
        ssl[tid]  = ss;
        nhil[tid] = -0.5f / ss;
        ltl[tid]  = -0.5f * __logf(ss) - HALF_LOG_2PI;
        if (tid == 0) sumWl = sW;
    }
    __syncthreads();                                        // B5

    if (iter < 3) {
        // ell[m] = log(act) + LSE_d(log_p) — serial over d, zero shuffles
        float lp[16];
        float M = NEG_BIG;
#pragma unroll
        for (int dd = 0; dd < 16; ++dd) {
            float df = v[dd] - mul[dd];
            lp[dd] = df * df * nhil[dd] + ltl[dd];
            M = fmaxf(M, lp[dd]);
        }
        float s = 0.f;
#pragma unroll
        for (int dd = 0; dd < 16; ++dd) s += __expf(lp[dd] - M);
        wsL[(size_t)(b * NN + n) * NM + tid] = lact + M + __logf(s);
    } else {
        const int f32 = *flagp;
        if (tid < 16) {
            if (f32) ((float*)outv)[(bn << 4) + tid] = mul[tid];
            else ((__hip_bfloat16*)outv)[(bn << 4) + tid] = __float2bfloat16(mul[tid]);
        }
        if (tid == 0) {
            float sumR = __expf(maxt) * sumWl;   // true sum_R (maxt <= 0)
            float bv = ldin(beta_v, n, f32);
            float c = 0.f;
#pragma unroll
            for (int dd = 0; dd < 16; ++dd) c += bv + __logf(ssl[dd]);
            c *= sumR;
            float lam = ldin(lambda_, 0, f32);
            float ba  = ldin(beta_a, n, f32);
            float ao  = 1.f / (1.f + __expf(-(lam * (ba - c))));
            int oi = NB * NN * ND + b * NN + n;
            if (f32) ((float*)outv)[oi] = ao;
            else ((__hip_bfloat16*)outv)[oi] = __float2bfloat16(ao);
        }
    }
}

// LSE over n of ell[b][n][m], one block per (b,m)
__global__ __launch_bounds__(256) void lse_kernel(const float* __restrict__ L,
                                                  float* __restrict__ LSE)
{
    __shared__ float col[NN];
    __shared__ float redw[4];
    const int tid = threadIdx.x;
    const int b = blockIdx.x / NM;
    const int m = blockIdx.x % NM;
    const float* base = L + (size_t)b * NN * NM + m;
    for (int n = tid; n < NN; n += 256) col[n] = base[(size_t)n * NM];
    __syncthreads();

    float mx = NEG_BIG;
    for (int n = tid; n < NN; n += 256) mx = fmaxf(mx, col[n]);
#pragma unroll
    for (int off = 32; off > 0; off >>= 1) mx = fmaxf(mx, __shfl_xor(mx, off));
    if ((tid & 63) == 0) redw[tid >> 6] = mx;
    __syncthreads();
    const float M = fmaxf(fmaxf(redw[0], redw[1]), fmaxf(redw[2], redw[3]));
    __syncthreads();

    float s = 0.f;
    for (int n = tid; n < NN; n += 256) s += __expf(col[n] - M);
#pragma unroll
    for (int off = 32; off > 0; off >>= 1) s += __shfl_xor(s, off);
    if ((tid & 63) == 0) redw[tid >> 6] = s;
    __syncthreads();
    if (tid == 0) {
        float S = (redw[0] + redw[1]) + (redw[2] + redw[3]);
        LSE[blockIdx.x] = M + __logf(S);
    }
}

extern "C" void kernel_launch(void* const* d_in, const int* in_sizes, int n_in,
                              void* d_out, int out_size, void* d_ws, size_t ws_size,
                              hipStream_t stream)
{
    const void* poses = d_in[0];
    const void* acts  = d_in[1];
    const void* lam   = d_in[2];
    const void* Wb    = d_in[3];
    const void* bv    = d_in[4];
    const void* ba    = d_in[5];

    float* ws  = (float*)d_ws;
    float* P   = ws + OFF_P;
    float* Wt  = ws + OFF_WT;
    float* A36 = ws + OFF_ACT;
    float* L   = ws + OFF_L;
    float* LSE = ws + OFF_LSE;
    int*  flag = (int*)(ws + OFF_FLAG);

    detect_kernel<<<1, 64, 0, stream>>>((const unsigned short*)poses, flag);

    prep_kernel<<<292, 256, 0, stream>>>(poses, acts, Wb, P, Wt, A36, flag);

    for (int it = 0; it < 4; ++it) {
        em_iter<<<NB * NN, 288, 0, stream>>>(P, Wt, A36, L, LSE, bv, ba, lam,
                                             d_out, flag, it);
        if (it < 3) {
            lse_kernel<<<NB * NM, 256, 0, stream>>>(L, LSE);
        }
    }
}

// Round 7
// 234.611 us; speedup vs baseline: 2.5851x; 1.1516x over previous
//
#include <hip/hip_runtime.h>
#include <hip/hip_bf16.h>

// Problem constants
#define NB   8      // batch
#define NM   288    // Bkk = 32*3*3
#define NN   1152   // Cww = 32*6*6
#define NUV  36     // w*w
#define ND   16

// ws layout (float offsets; P/Wt regions hold bf16 in half the space)
#define OFF_P    0
#define SZ_P     (NB*NUV*NM*ND)      // patches, bf16 [b][uv][m][k*4+j]
#define OFF_WT   (OFF_P + SZ_P)
#define SZ_WT    (32*NM*ND)          // W transposed, bf16 [z][m][i*4+j]
#define OFF_ACT  (OFF_WT + SZ_WT)
#define SZ_ACT   (NB*NUV*NM)         // log(act), f32 [b][uv][m]
#define OFF_L    (OFF_ACT + SZ_ACT)
#define SZ_L     (NB*NN*NM)          // ell, f32 [b][n][m] (em->em, contiguous)
#define OFF_LSE  (OFF_L + SZ_L)
#define SZ_LSE   (NB*NM)             // LSE over n, [b][m]
#define OFF_FLAG (OFF_LSE + SZ_LSE)  // dtype flag
#define OFF_LT   (OFF_FLAG + 16)
#define SZ_LT    (NB*NM*NN)          // ell transposed, f32 [b][m][n] (em->lse)
// total ~27.5 MB << ws_size (~256 MiB per harness poison WRITE_SIZE)

#define HALF_LOG_2PI 0.9189385332046727f
#define LOG_NN       7.049254841255839f   // log(1152)
#define NEG_BIG      (-1.0e30f)

__device__ __forceinline__ float ldin(const void* p, int i, int f32) {
    return f32 ? ((const float*)p)[i]
               : __bfloat162float(((const __hip_bfloat16*)p)[i]);
}

// unpack a bf16 pair held in a u32 into two floats (lossless)
__device__ __forceinline__ void unpk(unsigned u, float& lo, float& hi) {
    union { unsigned i; float f; } a, b;
    a.i = u << 16; b.i = u & 0xFFFF0000u;
    lo = a.f; hi = b.f;
}

// dtype sniff (r3-r5 verified: flag==0 on this harness; kept for safety)
__global__ void detect_kernel(const unsigned short* __restrict__ poses_u16,
                              int* __restrict__ flag) {
    if (blockIdx.x == 0 && threadIdx.x == 0) {
        int wild = 0;
        for (int i = 0; i < 64; ++i) {
            int ex = (poses_u16[i] >> 7) & 0xFF;
            if (ex >= 133) ++wild;
        }
        *flag = (wild >= 4) ? 1 : 0;
    }
}

// (b,s)-tiled prep: stage poses[b,:,s,:,:] + acts[b,s,:,:] in LDS, emit bf16 P
// and f32 log(act). Blocks 256..291 transpose W to bf16.
__global__ __launch_bounds__(256) void prep_kernel(
    const void* __restrict__ poses, const void* __restrict__ acts,
    const void* __restrict__ Wb, __hip_bfloat16* __restrict__ P,
    __hip_bfloat16* __restrict__ Wt, float* __restrict__ A36,
    const int* __restrict__ flagp)
{
    const int f32 = *flagp;
    const int blk = blockIdx.x;
    const int tid = threadIdx.x;
    if (blk < 256) {
        __shared__ float ps[16 * 196];
        __shared__ float asld[196];
        const int b = blk >> 5, s = blk & 31;
        for (int e = tid; e < 16 * 196; e += 256) {
            int c = e / 196, hw = e % 196;
            ps[e] = ldin(poses, ((b * 16 + c) * 32 + s) * 196 + hw, f32);
        }
        for (int e = tid; e < 196; e += 256)
            asld[e] = ldin(acts, (b * 32 + s) * 196 + e, f32);
        __syncthreads();
        for (int o = tid; o < 5184; o += 256) {
            int uv = o / 144, r = o % 144, xy = r >> 4, kj = r & 15;
            int u = uv / 6, vv2 = uv % 6;
            int x = xy / 3, y = xy % 3;
            int k = kj >> 2, j = kj & 3;
            int idx = u * 96 + vv2 * 16 + j * 4 + k;   // torch view scramble
            int c = idx / 36, rem = idx % 36;
            int wi = rem / 6, wj = rem % 6;
            P[((b * 36 + uv) * 288 + s * 9 + xy) * 16 + kj] =
                __float2bfloat16(ps[c * 196 + (2 * wi + x) * 14 + (2 * wj + y)]);
        }
        for (int o = tid; o < 324; o += 256) {
            int uv = o / 9, xy = o % 9;
            int u = uv / 6, vv2 = uv % 6;
            int x = xy / 3, y = xy % 3;
            A36[(b * 36 + uv) * 288 + s * 9 + xy] =
                __logf(asld[(2 * u + x) * 14 + (2 * vv2 + y)]);
        }
    } else {
        int idx = (blk - 256) * 256 + tid;    // 0..9215 (z,m) pairs
        int z = idx / 288, m = idx % 288;
        __hip_bfloat16* dst = &Wt[idx * 16];
#pragma unroll
        for (int e = 0; e < 16; ++e)
            dst[e] = __float2bfloat16(ldin(Wb, m * 512 + z * 16 + e, f32));
    }
}

// One block per (b,n). 288 threads; thread tid owns capsule m = tid.
// 3 barriers: half-wave shuffle max replaces the block-max stage; chunk
// partials are rescaled by exp(Mhw - M) at the combine (identical math).
__global__ __launch_bounds__(288, 4) void em_iter(
    const unsigned short* __restrict__ wsP, const unsigned short* __restrict__ wsWt,
    const float* __restrict__ wsA, float* __restrict__ wsL,
    float* __restrict__ wsLT, const float* __restrict__ wsLSE,
    const void* __restrict__ beta_v,
    const void* __restrict__ beta_a,
    const void* __restrict__ lambda_,
    void* __restrict__ outv, const int* __restrict__ flagp, int iter)
{
    __shared__ float red[NM * 17];   // [m][col]: 0..15 = v[d], 16 = w  (19.6 KB)
    __shared__ float Mhw[9];         // per-halfwave max of t
    __shared__ float paru[NM];       // [d][c] partial sum(w*v)
    __shared__ float parv[NM];       // [d][c] partial sum(w*v*v)
    __shared__ float paruW[18];      // [c] partial sum(w)
    __shared__ float mul[16], nhil[16], ltl[16], ssl[16];

    const int tid = threadIdx.x;          // == m
    const int bn  = blockIdx.x;
    const int b   = bn / NN;
    const int n   = bn % NN;
    const int z   = n / NUV;
    const int uv  = n % NUV;

    // all global loads issued up front (bf16 W/P: 32B each; L2-hot)
    const uint4* Wq = (const uint4*)(wsWt + ((z * NM + tid) << 4));
    const uint4* Pq = (const uint4*)(wsP + (((b * NUV + uv) * NM + tid) << 4));
    uint4 wq0 = Wq[0], wq1 = Wq[1];
    uint4 pq0 = Pq[0], pq1 = Pq[1];
    const float lact = wsA[(b * NUV + uv) * NM + tid];   // pre-logged in prep
    float t;
    if (iter == 0) t = lact - LOG_NN;
    else t = wsL[(size_t)(b * NN + n) * NM + tid] - wsLSE[b * NM + tid] + lact;
    t = fmaxf(t, NEG_BIG);   // finite even if act==0

    // half-wave (32-lane) max via shuffles — no barrier; wave 4 has 32 lanes
    float mhw = t;
#pragma unroll
    for (int off = 1; off < 32; off <<= 1)
        mhw = fmaxf(mhw, __shfl_xor(mhw, off, 32));
    const float w = __expf(t - mhw);        // per-halfwave scale; max elem = 1
    if ((tid & 31) == 0) Mhw[tid >> 5] = mhw;

    // unpack bf16 -> f32; votes v[i*4+k] = sum_j W[i][j] P[j][k].
    // LAYOUT: W_[i*4+j] (ij), P_[k*4+j] (kj, k-major!) — r6's bug was P_[j*4+k].
    float W_[16], P_[16], v[16];
    unpk(wq0.x, W_[0], W_[1]);   unpk(wq0.y, W_[2], W_[3]);
    unpk(wq0.z, W_[4], W_[5]);   unpk(wq0.w, W_[6], W_[7]);
    unpk(wq1.x, W_[8], W_[9]);   unpk(wq1.y, W_[10], W_[11]);
    unpk(wq1.z, W_[12], W_[13]); unpk(wq1.w, W_[14], W_[15]);
    unpk(pq0.x, P_[0], P_[1]);   unpk(pq0.y, P_[2], P_[3]);
    unpk(pq0.z, P_[4], P_[5]);   unpk(pq0.w, P_[6], P_[7]);
    unpk(pq1.x, P_[8], P_[9]);   unpk(pq1.y, P_[10], P_[11]);
    unpk(pq1.z, P_[12], P_[13]); unpk(pq1.w, P_[14], P_[15]);
#pragma unroll
    for (int i = 0; i < 4; ++i)
#pragma unroll
        for (int k = 0; k < 4; ++k)
            v[i * 4 + k] = W_[i * 4 + 0] * P_[k * 4 + 0] + W_[i * 4 + 1] * P_[k * 4 + 1]
                         + W_[i * 4 + 2] * P_[k * 4 + 2] + W_[i * 4 + 3] * P_[k * 4 + 3];

    // transpose: m-major stride 17 (odd -> bank-bijective, 2-way = free)
#pragma unroll
    for (int dd = 0; dd < 16; ++dd) red[tid * 17 + dd] = v[dd];
    red[tid * 17 + 16] = w;
    __syncthreads();                                        // B1

    // column sums: thread (d = tid&15, c = tid>>4) sums m = 16c..16c+15
    {
        const int d = tid & 15, c = tid >> 4;
        const float* base = &red[(c << 4) * 17];
        float s1 = 0.f, s2 = 0.f, sw = 0.f;
#pragma unroll
        for (int q = 0; q < 16; ++q) {
            float ww = base[q * 17 + 16];
            float vv = base[q * 17 + d];
            float t1 = ww * vv;
            s1 += t1; s2 += t1 * vv; sw += ww;
        }
        paru[d * 18 + c] = s1;
        parv[d * 18 + c] = s2;
        if (d == 0) paruW[c] = sw;
    }
    __syncthreads();                                        // B2

    float M_f = NEG_BIG, sW_f = 0.f;   // live into the output stage (tid<16)
    if (tid < 16) {
        float M = Mhw[0];
#pragma unroll
        for (int h = 1; h < 9; ++h) M = fmaxf(M, Mhw[h]);
        float sW = 0.f, S1 = 0.f, S2 = 0.f;
#pragma unroll
        for (int c = 0; c < 18; ++c) {
            float sc = __expf(Mhw[c >> 1] - M);   // chunk c lies in halfwave c>>1
            sW += paruW[c] * sc;
            S1 += paru[tid * 18 + c] * sc;
            S2 += parv[tid * 18 + c] * sc;
        }
        float mu = S1 / sW;
        float q2 = S2 / sW;
        float ss = fmaxf(q2 - mu * mu, 1e-30f);   // E[v^2]-mu^2 (r4/r5-verified)
        mul[tid]  = mu;
        ssl[tid]  = ss;
        nhil[tid] = -0.5f / ss;
        ltl[tid]  = -0.5f * __logf(ss) - HALF_LOG_2PI;
        M_f = M; sW_f = sW;
    }
    __syncthreads();                                        // B3

    if (iter < 3) {
        // ell[m] = log(act) + LSE_d(log_p) — serial in registers
        float lp[16];
        float M = NEG_BIG;
#pragma unroll
        for (int dd = 0; dd < 16; ++dd) {
            float df = v[dd] - mul[dd];
            lp[dd] = df * df * nhil[dd] + ltl[dd];
            M = fmaxf(M, lp[dd]);
        }
        float s = 0.f;
#pragma unroll
        for (int dd = 0; dd < 16; ++dd) s += __expf(lp[dd] - M);
        float ell = lact + M + __logf(s);
        wsL[(size_t)(b * NN + n) * NM + tid] = ell;            // contiguous (em->em)
        wsLT[((size_t)b * NM + tid) * NN + n] = ell;           // transposed (em->lse)
    } else {
        const int f32 = *flagp;
        if (tid < 16) {
            if (f32) ((float*)outv)[(bn << 4) + tid] = mul[tid];
            else ((__hip_bfloat16*)outv)[(bn << 4) + tid] = __float2bfloat16(mul[tid]);
        }
        if (tid == 0) {
            float sumR = __expf(M_f) * sW_f;   // true sum_R (M_f <= 0)
            float bv = ldin(beta_v, n, f32);
            float c = 0.f;
#pragma unroll
            for (int dd = 0; dd < 16; ++dd) c += bv + __logf(ssl[dd]);
            c *= sumR;
            float lam = ldin(lambda_, 0, f32);
            float ba  = ldin(beta_a, n, f32);
            float ao  = 1.f / (1.f + __expf(-(lam * (ba - c))));
            int oi = NB * NN * ND + b * NN + n;
            if (f32) ((float*)outv)[oi] = ao;
            else ((__hip_bfloat16*)outv)[oi] = __float2bfloat16(ao);
        }
    }
}

// LSE over n: wave-per-row on transposed LT[b][m][n] (fully coalesced).
// 576 blocks x 4 waves = 2304 rows.
__global__ __launch_bounds__(256) void lse_kernel(const float* __restrict__ LT,
                                                  float* __restrict__ LSE)
{
    const int row  = blockIdx.x * 4 + (threadIdx.x >> 6);   // b*NM + m
    const int lane = threadIdx.x & 63;
    const float* base = LT + (size_t)row * NN + lane;
    float vv[18];
    float mx = NEG_BIG;
#pragma unroll
    for (int i = 0; i < 18; ++i) { vv[i] = base[i * 64]; mx = fmaxf(mx, vv[i]); }
#pragma unroll
    for (int off = 1; off < 64; off <<= 1) mx = fmaxf(mx, __shfl_xor(mx, off));
    float s = 0.f;
#pragma unroll
    for (int i = 0; i < 18; ++i) s += __expf(vv[i] - mx);
#pragma unroll
    for (int off = 1; off < 64; off <<= 1) s += __shfl_xor(s, off);
    if (lane == 0) LSE[row] = mx + __logf(s);
}

extern "C" void kernel_launch(void* const* d_in, const int* in_sizes, int n_in,
                              void* d_out, int out_size, void* d_ws, size_t ws_size,
                              hipStream_t stream)
{
    const void* poses = d_in[0];
    const void* acts  = d_in[1];
    const void* lam   = d_in[2];
    const void* Wb    = d_in[3];
    const void* bv    = d_in[4];
    const void* ba    = d_in[5];

    float* ws  = (float*)d_ws;
    __hip_bfloat16* P  = (__hip_bfloat16*)(ws + OFF_P);
    __hip_bfloat16* Wt = (__hip_bfloat16*)(ws + OFF_WT);
    float* A36 = ws + OFF_ACT;
    float* L   = ws + OFF_L;
    float* LSE = ws + OFF_LSE;
    int*  flag = (int*)(ws + OFF_FLAG);
    float* LT  = ws + OFF_LT;

    detect_kernel<<<1, 64, 0, stream>>>((const unsigned short*)poses, flag);

    prep_kernel<<<292, 256, 0, stream>>>(poses, acts, Wb, P, Wt, A36, flag);

    for (int it = 0; it < 4; ++it) {
        em_iter<<<NB * NN, 288, 0, stream>>>((const unsigned short*)P,
                                             (const unsigned short*)Wt,
                                             A36, L, LT, LSE, bv, ba, lam,
                                             d_out, flag, it);
        if (it < 3) {
            lse_kernel<<<576, 256, 0, stream>>>(LT, LSE);
        }
    }
}